// Round 1
// baseline (309.273 us; speedup 1.0000x reference)
//
#include <hip/hip_runtime.h>
#include <math.h>

#define N_NODES 100000
#define NEDGE 64
#define NFEAT 11
#define EFEAT 30
#define MEM 64
#define TD 16
#define MSGIN 174
#define G3 192
#define WSTR 68
#define NB_BULK 128

__device__ __forceinline__ float sigmoidf_(float x) { return 1.f/(1.f+expf(-x)); }

// ---------------- bulk pass: E = sum(e), S[k] = sum(e * nf[:,k]) over all nodes ----------------
__global__ __launch_bounds__(256) void k_bulk(const float* __restrict__ nf,
    const float* __restrict__ Wnp, const float* __restrict__ bnp,
    const float* __restrict__ Wg, const float* __restrict__ bg,
    double* __restrict__ partials)
{
  __shared__ float sG[NFEAT];
  __shared__ float sCl;
  __shared__ float sTile[256*NFEAT];
  __shared__ float sW[4][12];
  int t = threadIdx.x;
  if (t < NFEAT) { float a = 0.f; for (int j=0;j<MEM;j++) a += Wnp[t*MEM+j]*Wg[j]; sG[t] = a; }
  if (t == NFEAT) { float a = bg[0]; for (int j=0;j<MEM;j++) a += bnp[j]*Wg[j]; sCl = a; }
  __syncthreads();
  float accE = 0.f, accS[NFEAT];
  #pragma unroll
  for (int k=0;k<NFEAT;k++) accS[k]=0.f;
  for (int base = blockIdx.x*256; base < N_NODES; base += NB_BULK*256) {
    int nrows = min(256, N_NODES - base);
    for (int i = t; i < nrows*NFEAT; i += 256) sTile[i] = nf[(long)base*NFEAT + i];
    __syncthreads();
    if (t < nrows) {
      float x[NFEAT];
      #pragma unroll
      for (int k=0;k<NFEAT;k++) x[k] = sTile[t*NFEAT+k];
      float l = sCl;
      #pragma unroll
      for (int k=0;k<NFEAT;k++) l += x[k]*sG[k];
      float e = expf(l);
      accE += e;
      #pragma unroll
      for (int k=0;k<NFEAT;k++) accS[k] += e*x[k];
    }
    __syncthreads();
  }
  #pragma unroll
  for (int off=32; off; off>>=1) {
    accE += __shfl_down(accE, off);
    #pragma unroll
    for (int k=0;k<NFEAT;k++) accS[k] += __shfl_down(accS[k], off);
  }
  int wv = t>>6;
  if ((t&63)==0) { sW[wv][0]=accE; for (int k=0;k<NFEAT;k++) sW[wv][1+k]=accS[k]; }
  __syncthreads();
  if (t < 12) {
    double d = (double)sW[0][t] + (double)sW[1][t] + (double)sW[2][t] + (double)sW[3][t];
    partials[blockIdx.x*12 + t] = d;
  }
}

// ---------------- sequential TGN scan over 64 edges + corrections ----------------
__global__ __launch_bounds__(256) void k_seq(
    const float* __restrict__ nf, const int* __restrict__ src, const int* __restrict__ dst,
    const float* __restrict__ ts, const float* __restrict__ ef,
    const float* __restrict__ Wnp, const float* __restrict__ bnp,
    const float* __restrict__ Wmsg, const float* __restrict__ bmsg,
    const float* __restrict__ Wih, const float* __restrict__ Whh,
    const float* __restrict__ bih, const float* __restrict__ bhh,
    const float* __restrict__ w0, const float* __restrict__ b0,
    const float* __restrict__ tW, const float* __restrict__ tB,
    const float* __restrict__ Wg, const float* __restrict__ bg,
    const float* __restrict__ Wp, const float* __restrict__ bp,
    double* __restrict__ corr)
{
  __shared__ float sH[128][MEM];          // local memory for touched slots
  __shared__ float sWih[G3][WSTR];        // W_ih rows (padded); reused as W_proj in P3
  __shared__ float sWhh[G3][WSTR];
  __shared__ float sEf[NEDGE][EFEAT];
  __shared__ float sTe[NEDGE][TD];
  __shared__ float sX[176];
  __shared__ float sMsg[MEM];
  __shared__ float sGi[G3], sGhs[G3], sGhd[G3];
  __shared__ float sBih[G3], sBhh[G3], sBmsg[MEM], sWgate[MEM];  // sBih reused as b_proj in P3
  __shared__ int sEp[128], sMap[128];
  __shared__ float sCrN[4][MEM];
  __shared__ float sCrD[4];
  __shared__ float sP1[2][12];
  __shared__ float sG2[NFEAT];
  __shared__ float sCl2;

  int t = threadIdx.x;
  int lane = t & 63, wv = t >> 6;
  float bgate = bg[0];

  // ---- P0: stage everything ----
  if (t < MEM) { sBmsg[t] = bmsg[t]; sWgate[t] = Wg[t]; }
  if (t < G3)  { sBih[t] = bih[t]; sBhh[t] = bhh[t]; }
  for (int i = t; i < G3*MEM; i += 256) { sWih[i>>6][i&63] = Wih[i]; sWhh[i>>6][i&63] = Whh[i]; }
  for (int i = t; i < NEDGE*EFEAT; i += 256) sEf[i/EFEAT][i%EFEAT] = ef[i];
  if (t < NEDGE) {
    float tt = ts[t];
    sTe[t][0] = tt*w0[0] + b0[0];
    for (int q = 0; q < TD-1; q++) sTe[t][1+q] = sinf(tt*tW[q] + tB[q]);
  }
  if (t < NEDGE) sEp[t] = src[t];
  else if (t < 128) sEp[t] = dst[t-64];
  if (t == 0) { sX[174] = 0.f; sX[175] = 0.f; }
  if (t >= 128 && t < 128+NFEAT) { int r = t-128; float a=0.f; for (int j=0;j<MEM;j++) a += Wnp[r*MEM+j]*Wg[j]; sG2[r]=a; }
  if (t == 128+NFEAT) { float a=bg[0]; for (int j=0;j<MEM;j++) a += bnp[j]*Wg[j]; sCl2=a; }
  __syncthreads();
  // first-occurrence map (canonical slot per node id)
  if (t < 128) {
    int id = sEp[t]; int fo = t;
    for (int j = 0; j < 128; j++) if (sEp[j] == id) { fo = j; break; }
    sMap[t] = fo;
  }
  // W_msg slice into registers: thread handles output mj, k-range [mk0, mk0+44)
  int mj = t >> 2, mg = t & 3, mk0 = mg*44;
  float wreg[44];
  #pragma unroll
  for (int kk = 0; kk < 44; kk++) {
    int k = mk0 + kk;
    wreg[kk] = (k < MSGIN) ? Wmsg[k*MEM + mj] : 0.f;
  }
  __syncthreads();
  // H init: mem0 = nf[id] @ W_np + b_np  for all 128 slots
  for (int p = t; p < 128*MEM; p += 256) {
    int i = p >> 6, j = p & 63;
    const float* row = nf + (long)sEp[i]*NFEAT;
    float a = bnp[j];
    #pragma unroll
    for (int k = 0; k < NFEAT; k++) a += row[k]*Wnp[k*MEM + j];
    sH[i][j] = a;
  }
  __syncthreads();

  // ---- P1: den0 / S0 (initial-memory contributions of canonical slots) ----
  {
    float e0 = 0.f, s0[NFEAT];
    #pragma unroll
    for (int k=0;k<NFEAT;k++) s0[k]=0.f;
    if (t < 128 && sMap[t] == t) {
      const float* row = nf + (long)sEp[t]*NFEAT;
      float l = sCl2;
      float x[NFEAT];
      #pragma unroll
      for (int k=0;k<NFEAT;k++) { x[k]=row[k]; l += x[k]*sG2[k]; }
      e0 = expf(l);
      #pragma unroll
      for (int k=0;k<NFEAT;k++) s0[k] = e0*x[k];
    }
    #pragma unroll
    for (int off=32; off; off>>=1) {
      e0 += __shfl_down(e0,off);
      #pragma unroll
      for (int k=0;k<NFEAT;k++) s0[k] += __shfl_down(s0[k],off);
    }
    if (lane==0 && wv<2) { sP1[wv][0]=e0; for(int k=0;k<NFEAT;k++) sP1[wv][1+k]=s0[k]; }
    __syncthreads();
    if (t < 12) corr[t] = (double)sP1[0][t] + (double)sP1[1][t];
  }

  // ---- P2: sequential edge loop ----
  for (int e = 0; e < NEDGE; e++) {
    int ss = sMap[e], dd = sMap[64+e];
    if (t < MSGIN) {
      float v;
      if (t < 64) v = sH[ss][t];
      else if (t < 128) v = sH[dd][t-64];
      else if (t < 158) v = sEf[e][t-128];
      else v = sTe[e][t-158];
      sX[t] = v;
    }
    __syncthreads();
    {
      float a0=0.f,a1=0.f,a2=0.f,a3=0.f;
      #pragma unroll
      for (int kk=0; kk<44; kk+=4) {
        a0 += wreg[kk]  * sX[mk0+kk];
        a1 += wreg[kk+1]* sX[mk0+kk+1];
        a2 += wreg[kk+2]* sX[mk0+kk+2];
        a3 += wreg[kk+3]* sX[mk0+kk+3];
      }
      float a = (a0+a1)+(a2+a3);
      a += __shfl_xor(a,1);
      a += __shfl_xor(a,2);
      if (mg == 0) sMsg[mj] = fmaxf(a + sBmsg[mj], 0.f);
    }
    __syncthreads();
    // gi = W_ih@msg, ghs = W_hh@h_s, ghd = W_hh@h_d  (576 dot-64s over 256 threads)
    for (int q = t; q < 576; q += 256) {
      const float* wrow; const float* v; float b; int r;
      if (q < 192)      { r = q;      wrow = sWih[r]; v = sMsg;   b = sBih[r]; }
      else if (q < 384) { r = q-192;  wrow = sWhh[r]; v = sH[ss]; b = sBhh[r]; }
      else              { r = q-384;  wrow = sWhh[r]; v = sH[dd]; b = sBhh[r]; }
      float a0=0.f,a1=0.f,a2=0.f,a3=0.f;
      #pragma unroll
      for (int k=0;k<MEM;k+=4) {
        a0 += wrow[k]*v[k];   a1 += wrow[k+1]*v[k+1];
        a2 += wrow[k+2]*v[k+2]; a3 += wrow[k+3]*v[k+3];
      }
      float s = (a0+a1)+(a2+a3) + b;
      if (q < 192) sGi[r] = s; else if (q < 384) sGhs[r] = s; else sGhd[r] = s;
    }
    __syncthreads();
    if (ss != dd) {
      if (t < 128) {
        int j = t & 63; int slot = (t < 64) ? ss : dd;
        const float* gh = (t < 64) ? sGhs : sGhd;
        float h = sH[slot][j];
        float r = sigmoidf_(sGi[j] + gh[j]);
        float z = sigmoidf_(sGi[64+j] + gh[64+j]);
        float n = tanhf(sGi[128+j] + r*gh[128+j]);
        sH[slot][j] = (1.f - z)*n + z*h;
      }
      __syncthreads();
    } else {
      if (t < 64) {
        float h = sH[ss][t];
        float r = sigmoidf_(sGi[t] + sGhs[t]);
        float z = sigmoidf_(sGi[64+t] + sGhs[64+t]);
        float n = tanhf(sGi[128+t] + r*sGhs[128+t]);
        sH[ss][t] = (1.f - z)*n + z*h;
      }
      __syncthreads();
      if (t < 192) {
        const float* wrow = sWhh[t]; const float* v = sH[ss];
        float a0=0.f,a1=0.f,a2=0.f,a3=0.f;
        #pragma unroll
        for (int k=0;k<MEM;k+=4){a0+=wrow[k]*v[k];a1+=wrow[k+1]*v[k+1];a2+=wrow[k+2]*v[k+2];a3+=wrow[k+3]*v[k+3];}
        sGhd[t] = (a0+a1)+(a2+a3) + sBhh[t];
      }
      __syncthreads();
      if (t < 64) {
        float h = sH[ss][t];
        float r = sigmoidf_(sGi[t] + sGhd[t]);
        float z = sigmoidf_(sGi[64+t] + sGhd[64+t]);
        float n = tanhf(sGi[128+t] + r*sGhd[128+t]);
        sH[ss][t] = (1.f - z)*n + z*h;
      }
      __syncthreads();
    }
  }

  // ---- P3: final-memory contributions (num1, den1). Reuse sWih as W_proj, sBih as b_proj ----
  for (int i = t; i < MEM*MEM; i += 256) sWih[i>>6][i&63] = Wp[i];
  if (t < MEM) sBih[t] = bp[t];
  __syncthreads();
  {
    float accN = 0.f, accD = 0.f;
    for (int it = 0; it < 32; it++) {
      int slot = it*4 + wv;
      int j = lane;
      bool used = (sMap[slot] == slot);
      float h = sH[slot][j];
      float vv = h * sWgate[j];
      #pragma unroll
      for (int off=32; off; off>>=1) vv += __shfl_xor(vv, off);
      float e1 = used ? expf(vv + bgate) : 0.f;
      float p = sBih[j];
      #pragma unroll 8
      for (int m=0;m<MEM;m++) p += sH[slot][m]*sWih[m][j];
      accN += e1*p;
      if (j == 0) accD += e1;
    }
    sCrN[wv][lane] = accN;
    if (lane == 0) sCrD[wv] = accD;
    __syncthreads();
    if (t < MEM) corr[13+t] = (double)sCrN[0][t]+(double)sCrN[1][t]+(double)sCrN[2][t]+(double)sCrN[3][t];
    if (t == MEM) corr[12] = (double)sCrD[0]+(double)sCrD[1]+(double)sCrD[2]+(double)sCrD[3];
  }
}

// ---------------- final combine ----------------
__global__ __launch_bounds__(64) void k_final(
    const double* __restrict__ partials, const double* __restrict__ corr,
    const float* __restrict__ Wnp, const float* __restrict__ bnp,
    const float* __restrict__ Wp, const float* __restrict__ bp,
    float* __restrict__ out)
{
  __shared__ double sTot[12];
  __shared__ double sT[MEM];
  int t = threadIdx.x;
  if (t < 12) {
    double d = 0.0;
    for (int b = 0; b < NB_BULK; b++) d += partials[b*12 + t];
    sTot[t] = d;
  }
  __syncthreads();
  double Eall = sTot[0] - corr[0];
  double Sd[NFEAT];
  #pragma unroll
  for (int k=0;k<NFEAT;k++) Sd[k] = sTot[1+k] - corr[1+k];
  {
    int m = t;
    double a = Eall * (double)bnp[m];
    #pragma unroll
    for (int k=0;k<NFEAT;k++) a += Sd[k]*(double)Wnp[k*MEM+m];
    sT[m] = a;
  }
  __syncthreads();
  {
    int j = t;
    double a = 0.0;
    for (int m=0;m<MEM;m++) a += sT[m]*(double)Wp[m*MEM+j];
    a += Eall*(double)bp[j] + corr[13+j];
    double den = Eall + corr[12];
    out[j] = (float)(a/den);
  }
}

extern "C" void kernel_launch(void* const* d_in, const int* in_sizes, int n_in,
                              void* d_out, int out_size, void* d_ws, size_t ws_size,
                              hipStream_t stream) {
  (void)in_sizes; (void)n_in; (void)out_size; (void)ws_size;
  const float* nf   = (const float*)d_in[0];
  const int*   src  = (const int*)d_in[1];
  const int*   dst  = (const int*)d_in[2];
  const float* ts   = (const float*)d_in[3];
  const float* ef   = (const float*)d_in[4];
  const float* Wnp  = (const float*)d_in[5];
  const float* bnp  = (const float*)d_in[6];
  const float* Wmsg = (const float*)d_in[7];
  const float* bmsg = (const float*)d_in[8];
  const float* Wih  = (const float*)d_in[9];
  const float* Whh  = (const float*)d_in[10];
  const float* bih  = (const float*)d_in[11];
  const float* bhh  = (const float*)d_in[12];
  const float* w0   = (const float*)d_in[13];
  const float* b0   = (const float*)d_in[14];
  const float* tW   = (const float*)d_in[15];
  const float* tB   = (const float*)d_in[16];
  const float* Wg   = (const float*)d_in[17];
  const float* bg   = (const float*)d_in[18];
  const float* Wp   = (const float*)d_in[19];
  const float* bp   = (const float*)d_in[20];
  double* partials = (double*)d_ws;
  double* corr = (double*)((char*)d_ws + (size_t)NB_BULK*12*sizeof(double));
  float* out = (float*)d_out;

  k_bulk<<<NB_BULK, 256, 0, stream>>>(nf, Wnp, bnp, Wg, bg, partials);
  k_seq<<<1, 256, 0, stream>>>(nf, src, dst, ts, ef, Wnp, bnp, Wmsg, bmsg,
                               Wih, Whh, bih, bhh, w0, b0, tW, tB, Wg, bg, Wp, bp, corr);
  k_final<<<1, 64, 0, stream>>>(partials, corr, Wnp, bnp, Wp, bp, out);
}

// Round 2
// 70.410 us; speedup vs baseline: 4.3924x; 4.3924x over previous
//
#include <hip/hip_runtime.h>
#include <math.h>

#define N_NODES 100000
#define NEDGE 64
#define NFEAT 11
#define EFEAT 30
#define MEM 64
#define TD 16
#define MSGIN 174
#define G3 192
#define NB_BULK 128

// d_ws layout
#define WS_STATES_OFF (NB_BULK * 12 * sizeof(double))            // after partials
#define WS_DONE_OFF   (WS_STATES_OFF + 128 * MEM * sizeof(float))

__device__ __forceinline__ float sigmoidf_(float x) { return 1.f/(1.f+expf(-x)); }

// ================= kernel 1: 64 edge blocks + 128 bulk blocks =================
__global__ __launch_bounds__(256) void k_main(
    const float* __restrict__ nf, const int* __restrict__ src, const int* __restrict__ dst,
    const float* __restrict__ ts, const float* __restrict__ ef,
    const float* __restrict__ Wnp, const float* __restrict__ bnp,
    const float* __restrict__ Wmsg, const float* __restrict__ bmsg,
    const float* __restrict__ Wih, const float* __restrict__ Whh,
    const float* __restrict__ bih, const float* __restrict__ bhh,
    const float* __restrict__ w0, const float* __restrict__ b0,
    const float* __restrict__ tW, const float* __restrict__ tB,
    const float* __restrict__ Wg, const float* __restrict__ bg,
    double* __restrict__ partials, float* __restrict__ states, int* __restrict__ done)
{
  int t = threadIdx.x;

  if (blockIdx.x >= NEDGE) {
    // ---------------- bulk pass: E = sum(e), S[k] = sum(e*nf[:,k]) ----------------
    __shared__ float sG[NFEAT];
    __shared__ float sCl;
    __shared__ float sTile[256*NFEAT];
    __shared__ float sW[4][12];
    int b = blockIdx.x - NEDGE;
    if (t < NFEAT) { float a = 0.f; for (int j=0;j<MEM;j++) a += Wnp[t*MEM+j]*Wg[j]; sG[t] = a; }
    if (t == NFEAT) { float a = bg[0]; for (int j=0;j<MEM;j++) a += bnp[j]*Wg[j]; sCl = a; }
    __syncthreads();
    float accE = 0.f, accS[NFEAT];
    #pragma unroll
    for (int k=0;k<NFEAT;k++) accS[k]=0.f;
    for (int base = b*256; base < N_NODES; base += NB_BULK*256) {
      int nrows = min(256, N_NODES - base);
      for (int i = t; i < nrows*NFEAT; i += 256) sTile[i] = nf[(long)base*NFEAT + i];
      __syncthreads();
      if (t < nrows) {
        float x[NFEAT];
        #pragma unroll
        for (int k=0;k<NFEAT;k++) x[k] = sTile[t*NFEAT+k];
        float l = sCl;
        #pragma unroll
        for (int k=0;k<NFEAT;k++) l += x[k]*sG[k];
        float e = expf(l);
        accE += e;
        #pragma unroll
        for (int k=0;k<NFEAT;k++) accS[k] += e*x[k];
      }
      __syncthreads();
    }
    #pragma unroll
    for (int off=32; off; off>>=1) {
      accE += __shfl_down(accE, off);
      #pragma unroll
      for (int k=0;k<NFEAT;k++) accS[k] += __shfl_down(accS[k], off);
    }
    int wv = t>>6;
    if ((t&63)==0) { sW[wv][0]=accE; for (int k=0;k<NFEAT;k++) sW[wv][1+k]=accS[k]; }
    __syncthreads();
    if (t < 12) {
      double d = (double)sW[0][t] + (double)sW[1][t] + (double)sW[2][t] + (double)sW[3][t];
      partials[b*12 + t] = d;
    }
    return;
  }

  // ---------------- edge block: one edge, dependency-resolved via flags ----------------
  __shared__ int sEp[128], sMap[128], sFirst[128];
  __shared__ float sX[176];              // [h_s 64 | h_d 64 | ef 30 | te 16 | pad 2]
  __shared__ float sMsg[MEM];
  __shared__ float sGi[G3], sGhs[G3], sGhd[G3];
  __shared__ float sNewS[MEM];

  int e = blockIdx.x;
  if (t < 64) sEp[t] = src[t];
  else if (t < 128) sEp[t] = dst[t-64];
  __syncthreads();
  if (t < 128) {
    int id = sEp[t]; int fo = t; int fe = t & 63;
    for (int i = 0; i < 128; i++) {
      if (sEp[i] == id) { if (i < fo) fo = i; int ei = i & 63; if (ei < fe) fe = ei; }
    }
    sMap[t] = fo; sFirst[t] = fe;
  }
  __syncthreads();
  int ss = sMap[e], dd = sMap[64+e];

  // spin on earlier conflicting edges (wave 0 lanes)
  if (t < e) {   // t < 64 implied (e <= 63)
    bool c = (sMap[t]==ss) || (sMap[t]==dd) || (sMap[64+t]==ss) || (sMap[64+t]==dd);
    if (c) {
      while (!__hip_atomic_load(&done[t], __ATOMIC_ACQUIRE, __HIP_MEMORY_SCOPE_AGENT))
        __builtin_amdgcn_s_sleep(2);
    }
  }
  __syncthreads();

  // load/init h_s, h_d; stage ef, te
  bool initS = (sFirst[ss] == e);
  bool initD = (sFirst[dd] == e);
  if (t < 64) {
    float v;
    if (initS) {
      const float* row = nf + (long)sEp[ss]*NFEAT;
      v = bnp[t];
      #pragma unroll
      for (int k = 0; k < NFEAT; k++) v += row[k]*Wnp[k*MEM + t];
    } else {
      v = __hip_atomic_load(&states[ss*MEM + t], __ATOMIC_RELAXED, __HIP_MEMORY_SCOPE_AGENT);
    }
    sX[t] = v;
  } else if (t < 128) {
    int j = t - 64; float v;
    if (initD) {
      const float* row = nf + (long)sEp[dd]*NFEAT;
      v = bnp[j];
      #pragma unroll
      for (int k = 0; k < NFEAT; k++) v += row[k]*Wnp[k*MEM + j];
    } else {
      v = __hip_atomic_load(&states[dd*MEM + j], __ATOMIC_RELAXED, __HIP_MEMORY_SCOPE_AGENT);
    }
    sX[t] = v;
  } else if (t < 158) {
    sX[t] = ef[e*EFEAT + (t-128)];
  } else if (t < 174) {
    int q = t - 158; float tt = ts[e];
    sX[t] = (q == 0) ? (tt*w0[0] + b0[0]) : sinf(tt*tW[q-1] + tB[q-1]);
  } else if (t < 176) sX[t] = 0.f;
  __syncthreads();

  // msg = relu(W_msg^T x + b): 4 threads per output, k-groups of 44 (same FP order as before)
  {
    int mj = t >> 2, mg = t & 3, mk0 = mg*44;
    float w[44];
    #pragma unroll
    for (int kk = 0; kk < 44; kk++) {
      int k = mk0 + kk;
      w[kk] = (k < MSGIN) ? Wmsg[k*MEM + mj] : 0.f;
    }
    float a0=0.f,a1=0.f,a2=0.f,a3=0.f;
    #pragma unroll
    for (int kk=0; kk<44; kk+=4) {
      a0 += w[kk]  * sX[mk0+kk];
      a1 += w[kk+1]* sX[mk0+kk+1];
      a2 += w[kk+2]* sX[mk0+kk+2];
      a3 += w[kk+3]* sX[mk0+kk+3];
    }
    float a = (a0+a1)+(a2+a3);
    a += __shfl_xor(a,1);
    a += __shfl_xor(a,2);
    if (mg == 0) sMsg[mj] = fmaxf(a + bmsg[mj], 0.f);
  }
  __syncthreads();

  // gates: thread r<192 computes gi[r], ghs[r], ghd[r]; weights streamed from L2 as float4
  if (t < G3) {
    const float4* wi4 = (const float4*)(Wih + t*MEM);
    const float4* wh4 = (const float4*)(Whh + t*MEM);
    float a0=0.f,a1=0.f,a2=0.f,a3=0.f;
    float b0v=0.f,b1v=0.f,b2v=0.f,b3v=0.f;
    float c0=0.f,c1=0.f,c2=0.f,c3=0.f;
    #pragma unroll
    for (int k = 0; k < MEM; k += 4) {
      float4 vi = wi4[k>>2];
      float4 vh = wh4[k>>2];
      a0 += vi.x*sMsg[k];   a1 += vi.y*sMsg[k+1];   a2 += vi.z*sMsg[k+2];   a3 += vi.w*sMsg[k+3];
      b0v+= vh.x*sX[k];     b1v+= vh.y*sX[k+1];     b2v+= vh.z*sX[k+2];     b3v+= vh.w*sX[k+3];
      c0 += vh.x*sX[64+k];  c1 += vh.y*sX[64+k+1];  c2 += vh.z*sX[64+k+2];  c3 += vh.w*sX[64+k+3];
    }
    sGi[t]  = (a0+a1)+(a2+a3) + bih[t];
    sGhs[t] = (b0v+b1v)+(b2v+b3v) + bhh[t];
    sGhd[t] = (c0+c1)+(c2+c3) + bhh[t];
  }
  __syncthreads();

  if (ss != dd) {
    if (t < 128) {
      int j = t & 63;
      bool iss = t < 64;
      float h = sX[t];
      const float* gh = iss ? sGhs : sGhd;
      float r = sigmoidf_(sGi[j] + gh[j]);
      float z = sigmoidf_(sGi[64+j] + gh[64+j]);
      float n = tanhf(sGi[128+j] + r*gh[128+j]);
      float hn = (1.f - z)*n + z*h;
      int slot = iss ? ss : dd;
      __hip_atomic_store(&states[slot*MEM + j], hn, __ATOMIC_RELAXED, __HIP_MEMORY_SCOPE_AGENT);
    }
  } else {
    if (t < 64) {
      float h = sX[t];
      float r = sigmoidf_(sGi[t] + sGhs[t]);
      float z = sigmoidf_(sGi[64+t] + sGhs[64+t]);
      float n = tanhf(sGi[128+t] + r*sGhs[128+t]);
      sNewS[t] = (1.f - z)*n + z*h;
    }
    __syncthreads();
    if (t < G3) {
      const float4* wh4 = (const float4*)(Whh + t*MEM);
      float b0v=0.f,b1v=0.f,b2v=0.f,b3v=0.f;
      #pragma unroll
      for (int k = 0; k < MEM; k += 4) {
        float4 vh = wh4[k>>2];
        b0v += vh.x*sNewS[k];  b1v += vh.y*sNewS[k+1];
        b2v += vh.z*sNewS[k+2]; b3v += vh.w*sNewS[k+3];
      }
      sGhd[t] = (b0v+b1v)+(b2v+b3v) + bhh[t];
    }
    __syncthreads();
    if (t < 64) {
      float h = sNewS[t];
      float r = sigmoidf_(sGi[t] + sGhd[t]);
      float z = sigmoidf_(sGi[64+t] + sGhd[64+t]);
      float n = tanhf(sGi[128+t] + r*sGhd[128+t]);
      float hn = (1.f - z)*n + z*h;
      __hip_atomic_store(&states[ss*MEM + t], hn, __ATOMIC_RELAXED, __HIP_MEMORY_SCOPE_AGENT);
    }
  }
  __threadfence();
  __syncthreads();
  if (t == 0) __hip_atomic_store(&done[e], 1, __ATOMIC_RELEASE, __HIP_MEMORY_SCOPE_AGENT);
}

// ================= kernel 2: readout (P1 initial sums, P3 final sums, combine) =================
__global__ __launch_bounds__(256) void k_post(
    const float* __restrict__ nf, const int* __restrict__ src, const int* __restrict__ dst,
    const float* __restrict__ Wnp, const float* __restrict__ bnp,
    const float* __restrict__ Wg, const float* __restrict__ bg,
    const float* __restrict__ Wp, const float* __restrict__ bp,
    const double* __restrict__ partials, const float* __restrict__ states,
    float* __restrict__ out)
{
  __shared__ float sH[128][MEM];
  __shared__ float sWp[MEM][68];
  __shared__ int sEp[128], sMap[128];
  __shared__ float sG2[NFEAT];
  __shared__ float sCl2;
  __shared__ float sWgate[MEM], sBpv[MEM];
  __shared__ float sP1[2][12];
  __shared__ float sCrN[4][MEM];
  __shared__ float sCrD[4];
  __shared__ double dCorr[12];
  __shared__ double sTot[12];
  __shared__ double sT[MEM];

  int t = threadIdx.x;
  int lane = t & 63, wv = t >> 6;
  float bgate = bg[0];

  if (t < 64) sEp[t] = src[t];
  else if (t < 128) sEp[t] = dst[t-64];
  if (t < MEM) { sWgate[t] = Wg[t]; sBpv[t] = bp[t]; }
  if (t >= 128 && t < 128+NFEAT) { int r = t-128; float a=0.f; for (int j=0;j<MEM;j++) a += Wnp[r*MEM+j]*Wg[j]; sG2[r]=a; }
  if (t == 128+NFEAT) { float a=bg[0]; for (int j=0;j<MEM;j++) a += bnp[j]*Wg[j]; sCl2=a; }
  __syncthreads();
  if (t < 128) {
    int id = sEp[t]; int fo = t;
    for (int i = 0; i < 128; i++) if (sEp[i] == id) { fo = i; break; }
    sMap[t] = fo;
  }
  __syncthreads();
  for (int p = t; p < 128*MEM; p += 256) {
    int i = p >> 6;
    sH[i][p & 63] = (sMap[i] == i) ? states[p] : 0.f;
  }
  for (int i = t; i < MEM*MEM; i += 256) sWp[i>>6][i&63] = Wp[i];

  // P1: initial-memory contributions of canonical slots
  {
    float e0 = 0.f, s0[NFEAT];
    #pragma unroll
    for (int k=0;k<NFEAT;k++) s0[k]=0.f;
    if (t < 128 && sMap[t] == t) {
      const float* row = nf + (long)sEp[t]*NFEAT;
      float l = sCl2;
      float x[NFEAT];
      #pragma unroll
      for (int k=0;k<NFEAT;k++) { x[k]=row[k]; l += x[k]*sG2[k]; }
      e0 = expf(l);
      #pragma unroll
      for (int k=0;k<NFEAT;k++) s0[k] = e0*x[k];
    }
    #pragma unroll
    for (int off=32; off; off>>=1) {
      e0 += __shfl_down(e0,off);
      #pragma unroll
      for (int k=0;k<NFEAT;k++) s0[k] += __shfl_down(s0[k],off);
    }
    if (lane==0 && wv<2) { sP1[wv][0]=e0; for(int k=0;k<NFEAT;k++) sP1[wv][1+k]=s0[k]; }
  }
  __syncthreads();
  if (t < 12) dCorr[t] = (double)sP1[0][t] + (double)sP1[1][t];

  // P3: final-memory contributions
  {
    float accN = 0.f, accD = 0.f;
    for (int it = 0; it < 32; it++) {
      int slot = it*4 + wv;
      int j = lane;
      bool used = (sMap[slot] == slot);
      float h = sH[slot][j];
      float vv = h * sWgate[j];
      #pragma unroll
      for (int off=32; off; off>>=1) vv += __shfl_xor(vv, off);
      float e1 = used ? expf(vv + bgate) : 0.f;
      float p = sBpv[j];
      #pragma unroll 8
      for (int m=0;m<MEM;m++) p += sH[slot][m]*sWp[m][j];
      accN += e1*p;
      if (j == 0) accD += e1;
    }
    sCrN[wv][lane] = accN;
    if (lane == 0) sCrD[wv] = accD;
  }
  __syncthreads();

  if (t < 12) {
    double d = 0.0;
    for (int b = 0; b < NB_BULK; b++) d += partials[b*12 + t];
    sTot[t] = d;
  }
  __syncthreads();
  if (t < MEM) {
    double Eall = sTot[0] - dCorr[0];
    double a = Eall * (double)bnp[t];
    #pragma unroll
    for (int k=0;k<NFEAT;k++) a += (sTot[1+k] - dCorr[1+k])*(double)Wnp[k*MEM+t];
    sT[t] = a;
  }
  __syncthreads();
  if (t < MEM) {
    double Eall = sTot[0] - dCorr[0];
    double num1 = (double)sCrN[0][t]+(double)sCrN[1][t]+(double)sCrN[2][t]+(double)sCrN[3][t];
    double den1 = (double)sCrD[0]+(double)sCrD[1]+(double)sCrD[2]+(double)sCrD[3];
    double a = 0.0;
    for (int m=0;m<MEM;m++) a += sT[m]*(double)Wp[m*MEM+t];
    a += Eall*(double)bp[t] + num1;
    out[t] = (float)(a/(Eall + den1));
  }
}

extern "C" void kernel_launch(void* const* d_in, const int* in_sizes, int n_in,
                              void* d_out, int out_size, void* d_ws, size_t ws_size,
                              hipStream_t stream) {
  (void)in_sizes; (void)n_in; (void)out_size; (void)ws_size;
  const float* nf   = (const float*)d_in[0];
  const int*   src  = (const int*)d_in[1];
  const int*   dst  = (const int*)d_in[2];
  const float* ts   = (const float*)d_in[3];
  const float* ef   = (const float*)d_in[4];
  const float* Wnp  = (const float*)d_in[5];
  const float* bnp  = (const float*)d_in[6];
  const float* Wmsg = (const float*)d_in[7];
  const float* bmsg = (const float*)d_in[8];
  const float* Wih  = (const float*)d_in[9];
  const float* Whh  = (const float*)d_in[10];
  const float* bih  = (const float*)d_in[11];
  const float* bhh  = (const float*)d_in[12];
  const float* w0   = (const float*)d_in[13];
  const float* b0   = (const float*)d_in[14];
  const float* tW   = (const float*)d_in[15];
  const float* tB   = (const float*)d_in[16];
  const float* Wg   = (const float*)d_in[17];
  const float* bg   = (const float*)d_in[18];
  const float* Wp   = (const float*)d_in[19];
  const float* bp   = (const float*)d_in[20];

  double* partials = (double*)d_ws;
  float*  states   = (float*)((char*)d_ws + WS_STATES_OFF);
  int*    done     = (int*)((char*)d_ws + WS_DONE_OFF);
  float*  out      = (float*)d_out;

  hipMemsetAsync(done, 0, NEDGE*sizeof(int), stream);
  k_main<<<NEDGE + NB_BULK, 256, 0, stream>>>(nf, src, dst, ts, ef, Wnp, bnp, Wmsg, bmsg,
                                              Wih, Whh, bih, bhh, w0, b0, tW, tB, Wg, bg,
                                              partials, states, done);
  k_post<<<1, 256, 0, stream>>>(nf, src, dst, Wnp, bnp, Wg, bg, Wp, bp, partials, states, out);
}